// Round 11
// baseline (217.960 us; speedup 1.0000x reference)
//
#include <hip/hip_runtime.h>

// EGNN layer, round 11: R10 + node_k packed 4 nodes/256-thr block under a
// gentle (256,4) bound (R9's spill was the (256,8) VGPR cap, and R10's loop
// holds no array -> immune), elist as ushort (gj < 65536).
// B=4, N=16384, E=65536, DH=128, DM=64.  NB = 65536 global nodes.

typedef unsigned short ushort_t;
typedef __attribute__((ext_vector_type(8))) short bf16x8;
typedef __attribute__((ext_vector_type(4))) float f32x4;
typedef _Float16 h2 __attribute__((ext_vector_type(2)));

__device__ __forceinline__ float fast_rcp(float v) { return __builtin_amdgcn_rcpf(v); }
__device__ __forceinline__ float fast_silu(float v) { return v * fast_rcp(1.0f + __expf(-v)); }
__device__ __forceinline__ ushort_t f2bf(float f) {
    unsigned u = __float_as_uint(f);
    u += 0x7fffu + ((u >> 16) & 1u);
    return (ushort_t)(u >> 16);
}
__device__ __forceinline__ float bf2f(ushort_t b) {
    return __uint_as_float(((unsigned)b) << 16);
}
__device__ __forceinline__ h2 u2h2(unsigned u) {
    union { unsigned u; h2 h; } v; v.u = u; return v.h;
}

// ---------------------------------------------------------------------------
// init: cursor=0 (65536) + weight transforms. 488*256 = 124928 threads exact.
// ---------------------------------------------------------------------------
__global__ __launch_bounds__(256) void init_k(const float* __restrict__ pe_w1,
                                              const float* __restrict__ pe_w2,
                                              const float* __restrict__ ph_w1,
                                              const float* __restrict__ ph_w2,
                                              int* __restrict__ cursor,
                                              ushort_t* __restrict__ W1t,
                                              ushort_t* __restrict__ Wp1t,
                                              ushort_t* __restrict__ Wp2t,
                                              unsigned* __restrict__ w2h) {
    int gg = blockIdx.x * 256 + threadIdx.x;
    if (gg < 65536) { cursor[gg] = 0; return; }
    int g = gg - 65536;
    if (g < 16384) {
        int c = g >> 7, k = g & 127;
        float v = (c < 64) ? pe_w1[k * 64 + c] : pe_w1[(128 + k) * 64 + (c - 64)];
        W1t[g] = f2bf(v);
    } else if (g < 40960) {
        int g2 = g - 16384;
        int n = g2 / 192, k = g2 - n * 192;
        Wp1t[g2] = f2bf(ph_w1[k * 128 + n]);
    } else if (g < 57344) {
        int g3 = g - 40960;
        int n = g3 >> 7, k = g3 & 127;
        Wp2t[g3] = f2bf(ph_w2[k * 128 + n]);
    } else if (g < 59392) {
        int g4 = g - 57344;
        int k2 = g4 >> 6, c = g4 & 63;
        union { unsigned u; _Float16 h[2]; } p;
        p.h[0] = (_Float16)pe_w2[(2 * k2) * 64 + c];
        p.h[1] = (_Float16)pe_w2[(2 * k2 + 1) * 64 + c];
        w2h[g4] = p.u;
    }
}

// ---------------------------------------------------------------------------
// scatter: elist[gi*64 + slot] = gj (ushort: gj in [0,65536))
// ---------------------------------------------------------------------------
__global__ __launch_bounds__(256) void scatter_k(const int* __restrict__ ei,
                                                 int* __restrict__ cursor,
                                                 ushort_t* __restrict__ elist) {
    int e = blockIdx.x * 256 + threadIdx.x;
    int2 sd = ((const int2*)ei)[e];
    int b = e >> 16;
    int gi = (b << 14) + sd.x;
    int gj = (b << 14) + sd.y;
    int slot = atomicAdd(&cursor[gi], 1);
    if (slot < 64) elist[gi * 64 + slot] = (ushort_t)gj;
}

// ---------------------------------------------------------------------------
// node kernel: 4 nodes per 256-thread block (one wave each), lane = feature.
// Inner loop identical to R10 (f16 dot2, w2h L1-hot reloads, no live array).
// wave_barrier-only LDS m-broadcast (waves have divergent deg — no syncthreads).
// ---------------------------------------------------------------------------
__global__ __launch_bounds__(256, 4) void node_k(const float* __restrict__ x,
                                                 const ushort_t* __restrict__ P,
                                                 const int* __restrict__ cursor,
                                                 const ushort_t* __restrict__ elist,
                                                 const float* __restrict__ w1,
                                                 const float* __restrict__ b1,
                                                 const unsigned* __restrict__ w2h,
                                                 const float* __restrict__ b2,
                                                 const float* __restrict__ pxw,
                                                 ushort_t* __restrict__ dh,
                                                 float* __restrict__ outx) {
    const int wid = threadIdx.x >> 6;
    const int lane = threadIdx.x & 63;
    const int n = blockIdx.x * 4 + wid;          // 0..65535
    __shared__ unsigned m_u_all[4][32];
    unsigned* m_u = m_u_all[wid];
    ushort_t* mh = (ushort_t*)m_u;

    const float w1r = w1[256 * 64 + lane];       // dist2 row of pe_w1
    const float b1v = b1[lane];
    const float b2v = b2[lane];
    const float pxv = pxw[lane];
    const float Pi = bf2f(P[(size_t)n * 128 + lane]);
    const float xi0 = x[n * 3 + 0];
    const float xi1 = x[n * 3 + 1];
    const float xi2 = x[n * 3 + 2];

    float dhacc = 0.0f;
    float dxp0 = 0.0f, dxp1 = 0.0f, dxp2 = 0.0f;
    const int dg = min(cursor[n], 64);
    const int base = n * 64;

    for (int t = 0; t < dg; t++) {
        int gj = (int)elist[base + t];                       // wave-uniform
        float Pj = bf2f(P[(size_t)gj * 128 + 64 + lane]);    // 128B/wave gather
        float ddx = xi0 - x[gj * 3 + 0];
        float ddy = xi1 - x[gj * 3 + 1];
        float ddz = xi2 - x[gj * 3 + 2];
        float d2 = fmaxf(ddx * ddx + ddy * ddy + ddz * ddz, 1e-12f);
        float m = fast_silu(Pi + Pj + d2 * w1r + b1v);
        __builtin_amdgcn_wave_barrier();
        union { ushort_t s; _Float16 h; } mc;
        mc.h = (_Float16)m;
        mh[lane] = mc.s;
        __builtin_amdgcn_wave_barrier();
        float s = b2v;
#pragma unroll
        for (int k2 = 0; k2 < 32; k2++) {
            h2 mm = u2h2(m_u[k2]);                           // LDS broadcast
            h2 ww = u2h2(w2h[k2 * 64 + lane]);               // coalesced, L1-hot
            s = __builtin_amdgcn_fdot2(mm, ww, s, false);
        }
        __builtin_amdgcn_wave_barrier();
        float m2 = fast_silu(s);
        dhacc += m2;
        float c = m2 * pxv * fast_rcp(sqrtf(d2) + 1e-8f);
        dxp0 = fmaf(c, ddx, dxp0);
        dxp1 = fmaf(c, ddy, dxp1);
        dxp2 = fmaf(c, ddz, dxp2);
    }

    dh[(size_t)n * 64 + lane] = f2bf(dhacc);                 // coalesced

    for (int off = 32; off; off >>= 1) {
        dxp0 += __shfl_down(dxp0, off);
        dxp1 += __shfl_down(dxp1, off);
        dxp2 += __shfl_down(dxp2, off);
    }
    if (lane == 0) {
        outx[n * 3 + 0] = xi0 + dxp0;
        outx[n * 3 + 1] = xi1 + dxp1;
        outx[n * 3 + 2] = xi2 + dxp2;
    }
}

// ---------------------------------------------------------------------------
// P-GEMM: P = h @ [W1_top|W1_mid] (bf16 out), optionally emits hb=bf16(h).
// ---------------------------------------------------------------------------
template <bool EMIT_BF16>
__global__ __launch_bounds__(256, 2) void pgemm_k(const float* __restrict__ A0,
                                                  const ushort_t* __restrict__ Wt,
                                                  ushort_t* __restrict__ outP,
                                                  ushort_t* __restrict__ hbout) {
    constexpr int KPAD = 40;
    __shared__ ushort_t As[128 * KPAD];
    __shared__ ushort_t Bs[128 * KPAD];
    const int tid = threadIdx.x;
    const int m0 = blockIdx.x * 128;
    const int wave = tid >> 6;
    const int lane = tid & 63;
    const int lr = lane & 15;
    const int lq = lane >> 4;

    f32x4 acc[2][8];
#pragma unroll
    for (int mt = 0; mt < 2; mt++)
#pragma unroll
        for (int nt = 0; nt < 8; nt++) { f32x4 z = {0.f,0.f,0.f,0.f}; acc[mt][nt] = z; }

    for (int k0 = 0; k0 < 128; k0 += 32) {
#pragma unroll
        for (int i = 0; i < 4; i++) {
            int lin = tid + i * 256;
            int m = lin >> 3;
            int kq = (lin & 7) * 4;
            float4 v = *(const float4*)(A0 + (size_t)(m0 + m) * 128 + k0 + kq);
            ushort4 w4;
            w4.x = f2bf(v.x); w4.y = f2bf(v.y); w4.z = f2bf(v.z); w4.w = f2bf(v.w);
            if (EMIT_BF16)
                *(ushort4*)(hbout + (size_t)(m0 + m) * 128 + k0 + kq) = w4;
            *(ushort4*)&As[m * KPAD + kq] = w4;
        }
#pragma unroll
        for (int i = 0; i < 2; i++) {
            int lin = tid + i * 256;
            int n = lin >> 2;
            int kq = (lin & 3) * 8;
            *(uint4*)&Bs[n * KPAD + kq] = *(const uint4*)(Wt + (size_t)n * 128 + k0 + kq);
        }
        __syncthreads();
        bf16x8 af[2], bfr[8];
#pragma unroll
        for (int mt = 0; mt < 2; mt++)
            af[mt] = *(const bf16x8*)&As[(wave * 32 + mt * 16 + lr) * KPAD + lq * 8];
#pragma unroll
        for (int nt = 0; nt < 8; nt++)
            bfr[nt] = *(const bf16x8*)&Bs[(nt * 16 + lr) * KPAD + lq * 8];
#pragma unroll
        for (int mt = 0; mt < 2; mt++)
#pragma unroll
            for (int nt = 0; nt < 8; nt++)
                acc[mt][nt] = __builtin_amdgcn_mfma_f32_16x16x32_bf16(af[mt], bfr[nt], acc[mt][nt], 0, 0, 0);
        __syncthreads();
    }
#pragma unroll
    for (int mt = 0; mt < 2; mt++)
#pragma unroll
        for (int nt = 0; nt < 8; nt++)
#pragma unroll
            for (int r = 0; r < 4; r++) {
                int row = m0 + wave * 32 + mt * 16 + lq * 4 + r;
                int col = nt * 16 + lr;
                outP[(size_t)row * 128 + col] = f2bf(acc[mt][nt][r]);
            }
}

// ---------------------------------------------------------------------------
// Fused node MLP: out_h = h + silu([h|dh]@W1 + b1) @ W2 + b2.
// Phase 1 -> t in LDS (bf16, pad 136); phase 2 from LDS. No t HBM round-trip.
// ---------------------------------------------------------------------------
template <bool USE_HB>
__global__ __launch_bounds__(256, 2) void mlp_fused_k(const float* __restrict__ h,
                                                      const ushort_t* __restrict__ hb,
                                                      const ushort_t* __restrict__ dh,
                                                      const ushort_t* __restrict__ Wp1t,
                                                      const float* __restrict__ b1,
                                                      const ushort_t* __restrict__ Wp2t,
                                                      const float* __restrict__ b2,
                                                      float* __restrict__ outh) {
    constexpr int KPAD = 40, TPAD = 136;
    __shared__ ushort_t As[128 * KPAD];
    __shared__ ushort_t Bs[128 * KPAD];
    __shared__ ushort_t Ts[128 * TPAD];
    const int tid = threadIdx.x;
    const int m0 = blockIdx.x * 128;
    const int wave = tid >> 6;
    const int lane = tid & 63;
    const int lr = lane & 15;
    const int lq = lane >> 4;

    f32x4 acc[2][8];
#pragma unroll
    for (int mt = 0; mt < 2; mt++)
#pragma unroll
        for (int nt = 0; nt < 8; nt++) { f32x4 z = {0.f,0.f,0.f,0.f}; acc[mt][nt] = z; }

    for (int k0 = 0; k0 < 192; k0 += 32) {
        if (USE_HB) {
#pragma unroll
            for (int i = 0; i < 2; i++) {
                int lin = tid + i * 256;
                int m = lin >> 2;
                int kq = (lin & 3) * 8;
                const ushort_t* src = (k0 >= 128)
                    ? dh + (size_t)(m0 + m) * 64 + (k0 - 128 + kq)
                    : hb + (size_t)(m0 + m) * 128 + k0 + kq;
                *(uint4*)&As[m * KPAD + kq] = *(const uint4*)src;
            }
        } else {
#pragma unroll
            for (int i = 0; i < 4; i++) {
                int lin = tid + i * 256;
                int m = lin >> 3;
                int kq = (lin & 7) * 4;
                ushort4 w4;
                if (k0 >= 128) {
                    w4 = *(const ushort4*)(dh + (size_t)(m0 + m) * 64 + (k0 - 128 + kq));
                } else {
                    float4 v = *(const float4*)(h + (size_t)(m0 + m) * 128 + k0 + kq);
                    w4.x = f2bf(v.x); w4.y = f2bf(v.y); w4.z = f2bf(v.z); w4.w = f2bf(v.w);
                }
                *(ushort4*)&As[m * KPAD + kq] = w4;
            }
        }
#pragma unroll
        for (int i = 0; i < 2; i++) {
            int lin = tid + i * 256;
            int n = lin >> 2;
            int kq = (lin & 3) * 8;
            *(uint4*)&Bs[n * KPAD + kq] = *(const uint4*)(Wp1t + (size_t)n * 192 + k0 + kq);
        }
        __syncthreads();
        bf16x8 af[2], bfr[8];
#pragma unroll
        for (int mt = 0; mt < 2; mt++)
            af[mt] = *(const bf16x8*)&As[(wave * 32 + mt * 16 + lr) * KPAD + lq * 8];
#pragma unroll
        for (int nt = 0; nt < 8; nt++)
            bfr[nt] = *(const bf16x8*)&Bs[(nt * 16 + lr) * KPAD + lq * 8];
#pragma unroll
        for (int mt = 0; mt < 2; mt++)
#pragma unroll
            for (int nt = 0; nt < 8; nt++)
                acc[mt][nt] = __builtin_amdgcn_mfma_f32_16x16x32_bf16(af[mt], bfr[nt], acc[mt][nt], 0, 0, 0);
        __syncthreads();
    }
#pragma unroll
    for (int mt = 0; mt < 2; mt++)
#pragma unroll
        for (int nt = 0; nt < 8; nt++)
#pragma unroll
            for (int r = 0; r < 4; r++) {
                int row = wave * 32 + mt * 16 + lq * 4 + r;
                int col = nt * 16 + lr;
                Ts[row * TPAD + col] = f2bf(fast_silu(acc[mt][nt][r] + b1[col]));
            }
    __syncthreads();

    f32x4 acc2[2][8];
#pragma unroll
    for (int mt = 0; mt < 2; mt++)
#pragma unroll
        for (int nt = 0; nt < 8; nt++) { f32x4 z = {0.f,0.f,0.f,0.f}; acc2[mt][nt] = z; }

    for (int k0 = 0; k0 < 128; k0 += 32) {
#pragma unroll
        for (int i = 0; i < 2; i++) {
            int lin = tid + i * 256;
            int n = lin >> 2;
            int kq = (lin & 3) * 8;
            *(uint4*)&Bs[n * KPAD + kq] = *(const uint4*)(Wp2t + (size_t)n * 128 + k0 + kq);
        }
        __syncthreads();
        bf16x8 af[2], bfr[8];
#pragma unroll
        for (int mt = 0; mt < 2; mt++)
            af[mt] = *(const bf16x8*)&Ts[(wave * 32 + mt * 16 + lr) * TPAD + k0 + lq * 8];
#pragma unroll
        for (int nt = 0; nt < 8; nt++)
            bfr[nt] = *(const bf16x8*)&Bs[(nt * 16 + lr) * KPAD + lq * 8];
#pragma unroll
        for (int mt = 0; mt < 2; mt++)
#pragma unroll
            for (int nt = 0; nt < 8; nt++)
                acc2[mt][nt] = __builtin_amdgcn_mfma_f32_16x16x32_bf16(af[mt], bfr[nt], acc2[mt][nt], 0, 0, 0);
        __syncthreads();
    }
#pragma unroll
    for (int mt = 0; mt < 2; mt++)
#pragma unroll
        for (int nt = 0; nt < 8; nt++)
#pragma unroll
            for (int r = 0; r < 4; r++) {
                int row = m0 + wave * 32 + mt * 16 + lq * 4 + r;
                int col = nt * 16 + lr;
                float v = acc2[mt][nt][r] + b2[col];
                if (USE_HB) v += bf2f(hb[(size_t)row * 128 + col]);
                else        v += h[(size_t)row * 128 + col];
                outh[(size_t)row * 128 + col] = v;
            }
}

// ---------------------------------------------------------------------------
extern "C" void kernel_launch(void* const* d_in, const int* in_sizes, int n_in,
                              void* d_out, int out_size, void* d_ws, size_t ws_size,
                              hipStream_t stream) {
    const float* x     = (const float*)d_in[0];
    const float* h     = (const float*)d_in[1];
    const int*   ei    = (const int*)d_in[2];
    const float* pe_w1 = (const float*)d_in[3];
    const float* pe_b1 = (const float*)d_in[4];
    const float* pe_w2 = (const float*)d_in[5];
    const float* pe_b2 = (const float*)d_in[6];
    const float* px_w  = (const float*)d_in[7];
    const float* ph_w1 = (const float*)d_in[8];
    const float* ph_b1 = (const float*)d_in[9];
    const float* ph_w2 = (const float*)d_in[10];
    const float* ph_b2 = (const float*)d_in[11];

    float* outx = (float*)d_out;                    // 4*16384*3
    float* outh = (float*)d_out + 196608;           // 4*16384*128

    // ws layout
    ushort_t* P    = (ushort_t*)d_ws;                     // 65536*128 bf16
    ushort_t* dh   = P + (size_t)65536 * 128;             // 65536*64 bf16
    int* cursor    = (int*)(dh + (size_t)65536 * 64);     // 65536 i32
    ushort_t* elist= (ushort_t*)(cursor + 65536);         // 65536*64 u16 (8 MB)
    ushort_t* W1t  = elist + (size_t)65536 * 64;          // 128*128 bf16
    ushort_t* Wp1t = W1t + 16384;                         // 128*192 bf16
    ushort_t* Wp2t = Wp1t + 24576;                        // 128*128 bf16
    unsigned* w2h  = (unsigned*)(Wp2t + 16384);           // 32*64 uint
    ushort_t* hb   = (ushort_t*)(w2h + 4096);             // 65536*128 bf16 (16 MB)
    size_t need_hb = (size_t)((char*)(hb + (size_t)65536 * 128) - (char*)d_ws);
    const bool use_hb = ws_size >= need_hb;

    init_k<<<488, 256, 0, stream>>>(pe_w1, pe_w2, ph_w1, ph_w2,
                                    cursor, W1t, Wp1t, Wp2t, w2h);
    if (use_hb)
        pgemm_k<true><<<512, 256, 0, stream>>>(h, W1t, P, hb);
    else
        pgemm_k<false><<<512, 256, 0, stream>>>(h, W1t, P, nullptr);
    scatter_k<<<1024, 256, 0, stream>>>(ei, cursor, elist);
    node_k<<<16384, 256, 0, stream>>>(x, P, cursor, elist,
                                      pe_w1, pe_b1, w2h, pe_b2, px_w,
                                      dh, outx);
    if (use_hb)
        mlp_fused_k<true><<<512, 256, 0, stream>>>(h, hb, dh, Wp1t, ph_b1,
                                                   Wp2t, ph_b2, outh);
    else
        mlp_fused_k<false><<<512, 256, 0, stream>>>(h, nullptr, dh, Wp1t, ph_b1,
                                                    Wp2t, ph_b2, outh);
}